// Round 8
// baseline (3653.130 us; speedup 1.0000x reference)
//
#include <hip/hip_runtime.h>

// Child-Sum Tree-LSTM, level-synchronous, B=8 L=8192 D=768.
// Per level: 5 fused K=768 GEMM products + LSTM cell epilogue.
//   acc0..2 (i,o,u) = hs @ (0.5*W_iou + U_iou)^T
//   acc3 (fl-pre)   = hl@Wfp^T + hr@Wfh^T,  Wfp = 0.5*W_f + U_f, Wfh = 0.5*W_f
//   acc4 (fr-pre)   = hl@Wfh^T + hr@Wfp^T
// fp16 MFMA 16x16x32, fp32 accum. Block = 128 rows x 64 cols, 256 thr
// (4 waves 2x2, wave tile 64x32). A-fragments load GLOBAL->REGISTER directly
// (reg double-buffer, issued one phase ahead; MFMA-layout-exact, 16x64B lines
// per load, wd-duplicate hits L1). LDS holds ONLY B (20KB/kt, dbuf 40KB) ->
// DS traffic -62% per block-kt. Counted vmcnt(13), raw barrier pair,
// sched_barrier(0) fences (rule 18), kt-loop unrolled x2 for static reg
// indexing (rule 20). mb-major bijective XCD order (FETCH -55%, r5).

typedef _Float16 half8 __attribute__((ext_vector_type(8)));
typedef float f32x4 __attribute__((ext_vector_type(4)));

#define ROWB 1536        // bytes per 768-elem fp16 row
#define NT 24            // 768 / 32
#define BUFB 20480       // B only: 5 mats x 32 pairs x 128B

__device__ __forceinline__ float sigm(float x){ return 1.f/(1.f+__expf(-x)); }
__device__ __forceinline__ float tanhfast(float x){ return 1.f - 2.f/(1.f+__expf(2.f*x)); }

__device__ __forceinline__ void gload16(const void* g, void* l){
  __builtin_amdgcn_global_load_lds((const __attribute__((address_space(1))) void*)g,
                                   (__attribute__((address_space(3))) void*)l, 16, 0, 0);
}

// Bw: 5 mats of 768x768 fp16: [0..2]=0.5*W_iou+U_iou (i,o,u), [3]=0.5*Wf+Uf, [4]=0.5*Wf
__global__ void prep_weights(const float* __restrict__ Wiou, const float* __restrict__ Uiou,
                             const float* __restrict__ Wf, const float* __restrict__ Uf,
                             _Float16* __restrict__ Bw)
{
    const int n1 = 2304 * 768, n2 = n1 + 589824, n3 = n2 + 589824;
    int stride = gridDim.x * blockDim.x;
    for (int idx = blockIdx.x * blockDim.x + threadIdx.x; idx < n3; idx += stride) {
        float v;
        if (idx < n1)      v = __fmaf_rn(0.5f, Wiou[idx], Uiou[idx]);
        else if (idx < n2) { int k = idx - n1; v = __fmaf_rn(0.5f, Wf[k], Uf[k]); }
        else               { int k = idx - n2; v = 0.5f * Wf[k]; }
        Bw[idx] = (_Float16)v;
    }
}

__global__ void cast_leaves(const float* __restrict__ x, _Float16* __restrict__ h, int n8)
{
    int stride = gridDim.x * blockDim.x;
    for (int i = blockIdx.x * blockDim.x + threadIdx.x; i < n8; i += stride) {
        float4 v0 = ((const float4*)x)[2 * i];
        float4 v1 = ((const float4*)x)[2 * i + 1];
        half8 o = { (_Float16)v0.x, (_Float16)v0.y, (_Float16)v0.z, (_Float16)v0.w,
                    (_Float16)v1.x, (_Float16)v1.y, (_Float16)v1.z, (_Float16)v1.w };
        ((half8*)h)[i] = o;
    }
}

// LDS per buffer (B only): 5 mats x 32 pairs x 128B (mat stride 4096).
// Pair p chunk j: jj=j^(p&7); col=d0+2p+(jj>>2), kchunk=jj&3.
__global__ __launch_bounds__(256, 2) void tree_level(
    const _Float16* __restrict__ Hc, const float* __restrict__ Cc,
    const _Float16* __restrict__ Bw,
    const float* __restrict__ biou, const float* __restrict__ bfv,
    _Float16* __restrict__ Hn, float* __restrict__ Cn,
    float* __restrict__ outH, float* __restrict__ outC,
    int M, int mblocks, int firstLevel, int finalLevel)
{
    __shared__ __align__(16) char smem[2 * BUFB];
    const int tid = threadIdx.x;
    const int lane = tid & 63;
    const int w = tid >> 6;        // 0..3
    const int wm = w >> 1;         // 0..1 row-wave (64 rows each)
    const int wd = w & 1;          // 0..1 col-wave (32 cols each)

    // bijective XCD chunking; mb-major within XCD
    const int nwg = mblocks * 12;
    const int orig = blockIdx.x;
    const int xcd = orig & 7, qx = nwg >> 3, rx = nwg & 7;
    const int v = (xcd < rx ? xcd * (qx + 1) : rx * (qx + 1) + (xcd - rx) * qx) + (orig >> 3);
    const int mb = v / 12;
    const int d0c = v - mb * 12;
    const int mBase = mb * 128;
    const int d0 = d0c * 64;

    // ---- A direct-to-reg addresses: frag row=lane&15, kchunk=lane>>4 ----
    const int lr16 = lane & 15;
    const int kch = lane >> 4;
    unsigned offHA[8];             // [fm*2 + side]
#pragma unroll
    for (int fm = 0; fm < 4; ++fm) {
        int rA = mBase + wm * 64 + fm * 16 + lr16;
        if (rA >= M) rA = M - 1;
#pragma unroll
        for (int side = 0; side < 2; ++side)
            offHA[fm * 2 + side] = (unsigned)(2 * rA + side) * ROWB + kch * 16;
    }
#define LOAD_A(ar, ko) do { _Pragma("unroll") for (int s = 0; s < 8; ++s) \
        ar[s] = *(const uint4*)((const char*)Hc + offHA[s] + (ko)); } while (0)

    // ---- B stage sources: slot s = mat s, pairs w*8+l3 ----
    const int l3 = lane >> 3, j = lane & 7;
    const int jj0 = j ^ l3;
    const int pB = w * 8 + l3;
    unsigned offWb[5];
#pragma unroll
    for (int s = 0; s < 5; ++s)
        offWb[s] = (unsigned)(s * 768 + d0 + 2 * pB + (jj0 >> 2)) * ROWB + (jj0 & 3) * 16;
    const int dstW = w * 1024;     // + s*4096, lane*16 by DMA

#define STAGE_B(bi, ko) do { _Pragma("unroll") for (int s = 0; s < 5; ++s) \
        gload16((const char*)Bw + offWb[s] + (ko), smem + (bi) * BUFB + s * 4096 + dstW); } while (0)

    // ---- B read offsets (kt-invariant) ----
    const int q = lane >> 4;
    int offB[2];
#pragma unroll
    for (int fd = 0; fd < 2; ++fd) {
        int cl = wd * 32 + fd * 16 + lr16;
        int p = cl >> 1;
        int jb = ((cl & 1) * 4 + q) ^ (p & 7);
        offB[fd] = p * 128 + jb * 16;
    }

    f32x4 acc[5][4][2];
#pragma unroll
    for (int g = 0; g < 5; ++g)
#pragma unroll
        for (int a = 0; a < 4; ++a)
#pragma unroll
            for (int b = 0; b < 2; ++b)
                acc[g][a][b] = (f32x4){0.f, 0.f, 0.f, 0.f};

#define COMPUTE(bb, ar) do { \
    _Pragma("unroll") for (int fd = 0; fd < 2; ++fd) { \
        const char* bp = (bb) + offB[fd]; \
        half8 b0 = *(const half8*)(bp); \
        half8 b1 = *(const half8*)(bp + 4096); \
        half8 b2 = *(const half8*)(bp + 8192); \
        half8 b3 = *(const half8*)(bp + 12288); \
        half8 b4 = *(const half8*)(bp + 16384); \
        _Pragma("unroll") for (int fm = 0; fm < 4; ++fm) { \
            half8 hl = __builtin_bit_cast(half8, ar[fm * 2]); \
            half8 hr = __builtin_bit_cast(half8, ar[fm * 2 + 1]); \
            acc[3][fm][fd] = __builtin_amdgcn_mfma_f32_16x16x32_f16(hl, b3, acc[3][fm][fd], 0, 0, 0); \
            acc[4][fm][fd] = __builtin_amdgcn_mfma_f32_16x16x32_f16(hl, b4, acc[4][fm][fd], 0, 0, 0); \
            half8 hs = hl + hr; \
            acc[0][fm][fd] = __builtin_amdgcn_mfma_f32_16x16x32_f16(hs, b0, acc[0][fm][fd], 0, 0, 0); \
            acc[1][fm][fd] = __builtin_amdgcn_mfma_f32_16x16x32_f16(hs, b1, acc[1][fm][fd], 0, 0, 0); \
            acc[2][fm][fd] = __builtin_amdgcn_mfma_f32_16x16x32_f16(hs, b2, acc[2][fm][fd], 0, 0, 0); \
            acc[3][fm][fd] = __builtin_amdgcn_mfma_f32_16x16x32_f16(hr, b4, acc[3][fm][fd], 0, 0, 0); \
            acc[4][fm][fd] = __builtin_amdgcn_mfma_f32_16x16x32_f16(hr, b3, acc[4][fm][fd], 0, 0, 0); \
        } \
    } } while (0)

    // ---- main loop: reg-dbuf A, LDS-dbuf B, counted vmcnt, unrolled x2 ----
    uint4 a0[8], a1[8];
    STAGE_B(0, 0);
    LOAD_A(a0, 0);
    for (int it = 0; it < 12; ++it) {
        const int kt = 2 * it;
        // phase even: compute buf0/a0, prefetch kt+1 into buf1/a1
        STAGE_B(1, (kt + 1) * 64);
        LOAD_A(a1, (kt + 1) * 64);
        asm volatile("s_waitcnt vmcnt(13)" ::: "memory");   // all of kt's loads landed
        __builtin_amdgcn_sched_barrier(0);
        __builtin_amdgcn_s_barrier();
        COMPUTE(smem, a0);
        __builtin_amdgcn_s_barrier();
        // phase odd: compute buf1/a1, prefetch kt+2 into buf0/a0
        if (it < 11) {
            STAGE_B(0, (kt + 2) * 64);
            LOAD_A(a0, (kt + 2) * 64);
            asm volatile("s_waitcnt vmcnt(13)" ::: "memory");
        } else {
            asm volatile("s_waitcnt vmcnt(0)" ::: "memory");
        }
        __builtin_amdgcn_sched_barrier(0);
        __builtin_amdgcn_s_barrier();
        COMPUTE(smem + BUFB, a1);
        if (it < 11) __builtin_amdgcn_s_barrier();
    }

    // ---- LSTM cell epilogue, in-register ----
#pragma unroll
    for (int fd = 0; fd < 2; ++fd) {
        const int col = d0 + wd * 32 + fd * 16 + lr16;
        const float bi = biou[col];
        const float bo = biou[768 + col];
        const float bu = biou[1536 + col];
        const float bf = bfv[col];
#pragma unroll
        for (int fm = 0; fm < 4; ++fm) {
            const int rb = mBase + wm * 64 + fm * 16 + q * 4;
#pragma unroll
            for (int r4 = 0; r4 < 4; ++r4) {
                int row = rb + r4;
                if (row < M) {
                    float iv = acc[0][fm][fd][r4] + bi;
                    float ov = acc[1][fm][fd][r4] + bo;
                    float uv = acc[2][fm][fd][r4] + bu;
                    float fl = sigm(acc[3][fm][fd][r4] + bf);
                    float fr = sigm(acc[4][fm][fd][r4] + bf);
                    float clv = 0.f, crv = 0.f;
                    if (!firstLevel) {
                        clv = Cc[(size_t)(2 * row) * 768 + col];
                        crv = Cc[(size_t)(2 * row + 1) * 768 + col];
                    }
                    float c = sigm(iv) * tanhfast(uv) + fl * clv + fr * crv;
                    float h = sigm(ov) * tanhfast(c);
                    if (finalLevel) {
                        outH[row * 768 + col] = h;
                        outC[row * 768 + col] = c;
                    } else {
                        Hn[(size_t)row * 768 + col] = (_Float16)h;
                        Cn[(size_t)row * 768 + col] = c;
                    }
                }
            }
        }
    }
}

extern "C" void kernel_launch(void* const* d_in, const int* in_sizes, int n_in,
                              void* d_out, int out_size, void* d_ws, size_t ws_size,
                              hipStream_t stream)
{
    const float* leaf = (const float*)d_in[0];
    const float* Wiou = (const float*)d_in[1];
    const float* biou = (const float*)d_in[2];
    const float* Uiou = (const float*)d_in[3];
    const float* Wf   = (const float*)d_in[4];
    const float* bfv  = (const float*)d_in[5];
    const float* Uf   = (const float*)d_in[6];

    char* ws = (char*)d_ws;
    _Float16* Bw = (_Float16*)(ws);                  // 5x768x768 fp16 = 5,898,240 B
    _Float16* H0 = (_Float16*)(ws + 5898240);        // 65536x768 fp16
    _Float16* H1 = (_Float16*)(ws + 106561536);      // 32768x768 fp16
    float*    C0 = (float*)(ws + 156893184);         // 32768x768 f32
    float*    C1 = (float*)(ws + 257556480);         // 16384x768 f32

    prep_weights<<<1024, 256, 0, stream>>>(Wiou, Uiou, Wf, Uf, Bw);
    cast_leaves<<<2048, 256, 0, stream>>>(leaf, H0, 50331648 / 8);

    float* out = (float*)d_out;  // [2,8,768]
    _Float16* Hc = H0; _Float16* Hn = H1;
    float* Cc = C1; float* Cn = C0;
    int rows = 65536, level = 0;
    while (rows > 8) {
        int M = rows >> 1;
        int fin = (M == 8) ? 1 : 0;
        int mblocks = (M + 127) / 128;
        tree_level<<<mblocks * 12, 256, 0, stream>>>(Hc, Cc, Bw, biou, bfv,
            Hn, Cn, fin ? out : (float*)nullptr, fin ? out + 6144 : (float*)nullptr,
            M, mblocks, level == 0 ? 1 : 0, fin);
        _Float16* th = Hc; Hc = Hn; Hn = th;
        float* tc = Cc; Cc = Cn; Cn = tc;
        rows = M; ++level;
    }
}

// Round 9
// 1334.281 us; speedup vs baseline: 2.7379x; 2.7379x over previous
//
#include <hip/hip_runtime.h>

// Child-Sum Tree-LSTM, level-synchronous, B=8 L=8192 D=768.
// Per level: 5 fused K=768 GEMM products + LSTM cell epilogue.
//   acc0..2 (i,o,u) = hs @ (0.5*W_iou + U_iou)^T
//   acc3 (fl-pre)   = hl@Wfp^T + hr@Wfh^T,  Wfp = 0.5*W_f + U_f, Wfh = 0.5*W_f
//   acc4 (fr-pre)   = hl@Wfh^T + hr@Wfp^T
// fp16 MFMA 16x16x32, fp32 accum.
// R9: m201-style phase-split port. Block = 128 rows x 128 cols, 512 thr
// (8 waves 2Mx4N, wave tile 64x32, acc 160). LDS 2x57.3KB -> 1 block/CU.
// Per kt: 4 phases (by fm): {ds_read hl/hr (+10 B-frags & 7-load STAGE in
// ph0) -> s_barrier -> setprio(1) 14 MFMA setprio(0) -> s_barrier}; vmcnt(0)
// only at phase-3 end (3-phase landing window). Source-side XOR swizzle,
// linear LDS dest (rule 21), mb-major bijective XCD order.

typedef _Float16 half8 __attribute__((ext_vector_type(8)));
typedef float f32x4 __attribute__((ext_vector_type(4)));

#define ROWB 1536        // bytes per 768-elem fp16 row
#define NT 24            // 768 / 32
#define BUFB 57344       // A 16384 + B 40960
#define BOFF 16384

__device__ __forceinline__ float sigm(float x){ return 1.f/(1.f+__expf(-x)); }
__device__ __forceinline__ float tanhfast(float x){ return 1.f - 2.f/(1.f+__expf(2.f*x)); }

__device__ __forceinline__ void gload16(const void* g, void* l){
  __builtin_amdgcn_global_load_lds((const __attribute__((address_space(1))) void*)g,
                                   (__attribute__((address_space(3))) void*)l, 16, 0, 0);
}

// Bw: 5 mats of 768x768 fp16: [0..2]=0.5*W_iou+U_iou (i,o,u), [3]=0.5*Wf+Uf, [4]=0.5*Wf
__global__ void prep_weights(const float* __restrict__ Wiou, const float* __restrict__ Uiou,
                             const float* __restrict__ Wf, const float* __restrict__ Uf,
                             _Float16* __restrict__ Bw)
{
    const int n1 = 2304 * 768, n2 = n1 + 589824, n3 = n2 + 589824;
    int stride = gridDim.x * blockDim.x;
    for (int idx = blockIdx.x * blockDim.x + threadIdx.x; idx < n3; idx += stride) {
        float v;
        if (idx < n1)      v = __fmaf_rn(0.5f, Wiou[idx], Uiou[idx]);
        else if (idx < n2) { int k = idx - n1; v = __fmaf_rn(0.5f, Wf[k], Uf[k]); }
        else               { int k = idx - n2; v = 0.5f * Wf[k]; }
        Bw[idx] = (_Float16)v;
    }
}

__global__ void cast_leaves(const float* __restrict__ x, _Float16* __restrict__ h, int n8)
{
    int stride = gridDim.x * blockDim.x;
    for (int i = blockIdx.x * blockDim.x + threadIdx.x; i < n8; i += stride) {
        float4 v0 = ((const float4*)x)[2 * i];
        float4 v1 = ((const float4*)x)[2 * i + 1];
        half8 o = { (_Float16)v0.x, (_Float16)v0.y, (_Float16)v0.z, (_Float16)v0.w,
                    (_Float16)v1.x, (_Float16)v1.y, (_Float16)v1.z, (_Float16)v1.w };
        ((half8*)h)[i] = o;
    }
}

// LDS per buffer:
//  A: 128 rows x 128B. Row r chunk c: jj=c^(r&7); side=jj>>2 (0=HL,1=HR),
//     kchunk=jj&3 of H row 2*(mBase+r)+side.
//  B at +16384: 5 mats x 64 pairs x 128B (mat stride 8192). Pair p chunk c:
//     jj=c^(p&7); col=d0+2p+(jj>>2), kchunk=jj&3.
__global__ __launch_bounds__(512, 2) void tree_level(
    const _Float16* __restrict__ Hc, const float* __restrict__ Cc,
    const _Float16* __restrict__ Bw,
    const float* __restrict__ biou, const float* __restrict__ bfv,
    _Float16* __restrict__ Hn, float* __restrict__ Cn,
    float* __restrict__ outH, float* __restrict__ outC,
    int M, int mblocks, int firstLevel, int finalLevel)
{
    __shared__ __align__(16) char smem[2 * BUFB];
    const int tid = threadIdx.x;
    const int lane = tid & 63;
    const int w = tid >> 6;        // 0..7
    const int wm = w >> 2;         // 0..1 row-wave (64 rows)
    const int wd = w & 3;          // 0..3 col-wave (32 cols)

    // bijective XCD chunking; mb-major within XCD (6 same-mb blocks adjacent)
    const int nwg = mblocks * 6;
    const int orig = blockIdx.x;
    const int xcd = orig & 7, qx = nwg >> 3, rx = nwg & 7;
    const int v = (xcd < rx ? xcd * (qx + 1) : rx * (qx + 1) + (xcd - rx) * qx) + (orig >> 3);
    const int mb = v / 6;
    const int d0c = v - mb * 6;
    const int mBase = mb * 128;
    const int d0 = d0c * 128;

    // ---- stage-source precompute: 7 loads/thread (2 A + 5 B) ----
    const int l3 = lane >> 3, j = lane & 7;
    const int jj0 = j ^ l3;        // (r&7)==l3 and (p&7)==l3 by construction
    unsigned offHa[2];
#pragma unroll
    for (int s = 0; s < 2; ++s) {
        int gr = mBase + w * 16 + s * 8 + l3;
        if (gr >= M) gr = M - 1;
        offHa[s] = (unsigned)(2 * gr + (jj0 >> 2)) * ROWB + (jj0 & 3) * 16;
    }
    const int pB = w * 8 + l3;
    unsigned offWb[5];
#pragma unroll
    for (int t = 0; t < 5; ++t)
        offWb[t] = (unsigned)(t * 768 + d0 + 2 * pB + (jj0 >> 2)) * ROWB + (jj0 & 3) * 16;

#define STAGE(bi, ko) do { \
    _Pragma("unroll") for (int s = 0; s < 2; ++s) \
        gload16((const char*)Hc + offHa[s] + (ko), smem + (bi) * BUFB + w * 2048 + s * 1024); \
    _Pragma("unroll") for (int t = 0; t < 5; ++t) \
        gload16((const char*)Bw + offWb[t] + (ko), smem + (bi) * BUFB + BOFF + t * 8192 + w * 1024); \
} while (0)

    // ---- compute offsets (kt-invariant) ----
    const int q = lane >> 4;       // 0..3 K-slice / C-row-group
    const int lr16 = lane & 15;
    int offA[4];
#pragma unroll
    for (int fm = 0; fm < 4; ++fm) {
        int r = wm * 64 + fm * 16 + lr16;
        offA[fm] = r * 128 + ((q ^ (r & 7)) * 16);
    }
    int offB[2];
#pragma unroll
    for (int fd = 0; fd < 2; ++fd) {
        int cl = wd * 32 + fd * 16 + lr16;
        int p = cl >> 1;
        int jb = ((cl & 1) * 4 + q) ^ (p & 7);
        offB[fd] = BOFF + p * 128 + jb * 16;
    }

    f32x4 acc[5][4][2];
#pragma unroll
    for (int g = 0; g < 5; ++g)
#pragma unroll
        for (int a = 0; a < 4; ++a)
#pragma unroll
            for (int b2 = 0; b2 < 2; ++b2)
                acc[g][a][b2] = (f32x4){0.f, 0.f, 0.f, 0.f};

#define MFMA_FM(p) do { \
    _Pragma("unroll") for (int fd = 0; fd < 2; ++fd) { \
        acc[3][p][fd] = __builtin_amdgcn_mfma_f32_16x16x32_f16(hl, b[fd][3], acc[3][p][fd], 0, 0, 0); \
        acc[4][p][fd] = __builtin_amdgcn_mfma_f32_16x16x32_f16(hl, b[fd][4], acc[4][p][fd], 0, 0, 0); \
        acc[0][p][fd] = __builtin_amdgcn_mfma_f32_16x16x32_f16(hs, b[fd][0], acc[0][p][fd], 0, 0, 0); \
        acc[1][p][fd] = __builtin_amdgcn_mfma_f32_16x16x32_f16(hs, b[fd][1], acc[1][p][fd], 0, 0, 0); \
        acc[2][p][fd] = __builtin_amdgcn_mfma_f32_16x16x32_f16(hs, b[fd][2], acc[2][p][fd], 0, 0, 0); \
        acc[3][p][fd] = __builtin_amdgcn_mfma_f32_16x16x32_f16(hr, b[fd][4], acc[3][p][fd], 0, 0, 0); \
        acc[4][p][fd] = __builtin_amdgcn_mfma_f32_16x16x32_f16(hr, b[fd][3], acc[4][p][fd], 0, 0, 0); \
    } } while (0)

    // ---- main loop: 4 phases per kt (m201-style) ----
    STAGE(0, 0);
    asm volatile("s_waitcnt vmcnt(0)" ::: "memory");
    __builtin_amdgcn_s_barrier();
    for (int kt = 0; kt < NT; ++kt) {
        const char* bb = smem + (kt & 1) * BUFB;
        const int nbi = (kt & 1) ^ 1;
        half8 b[2][5];
        half8 hl, hr, hs;

        // ---- phase 0 (fm=0): A0 + all B frags + stage issue ----
        hl = *(const half8*)(bb + offA[0]);
        hr = *(const half8*)(bb + (offA[0] ^ 64));
#pragma unroll
        for (int fd = 0; fd < 2; ++fd)
#pragma unroll
            for (int t = 0; t < 5; ++t)
                b[fd][t] = *(const half8*)(bb + offB[fd] + t * 8192);
        if (kt + 1 < NT) STAGE(nbi, (kt + 1) * 64);
        __builtin_amdgcn_sched_barrier(0);
        __builtin_amdgcn_s_barrier();
        __builtin_amdgcn_sched_barrier(0);
        __builtin_amdgcn_s_setprio(1);
        hs = hl + hr;
        MFMA_FM(0);
        __builtin_amdgcn_s_setprio(0);
        __builtin_amdgcn_sched_barrier(0);
        __builtin_amdgcn_s_barrier();

        // ---- phases 1..3 (fm=p): 2 ds_read + 14 MFMA each ----
#pragma unroll
        for (int p = 1; p < 4; ++p) {
            hl = *(const half8*)(bb + offA[p]);
            hr = *(const half8*)(bb + (offA[p] ^ 64));
            __builtin_amdgcn_sched_barrier(0);
            __builtin_amdgcn_s_barrier();
            __builtin_amdgcn_sched_barrier(0);
            __builtin_amdgcn_s_setprio(1);
            hs = hl + hr;
            MFMA_FM(p);
            __builtin_amdgcn_s_setprio(0);
            __builtin_amdgcn_sched_barrier(0);
            if (p == 3) asm volatile("s_waitcnt vmcnt(0)" ::: "memory");  // next buf landed
            __builtin_amdgcn_s_barrier();
        }
    }

    // ---- LSTM cell epilogue, in-register ----
#pragma unroll
    for (int fd = 0; fd < 2; ++fd) {
        const int col = d0 + wd * 32 + fd * 16 + lr16;
        const float bi = biou[col];
        const float bo = biou[768 + col];
        const float bu = biou[1536 + col];
        const float bf = bfv[col];
#pragma unroll
        for (int fm = 0; fm < 4; ++fm) {
            const int rb = mBase + wm * 64 + fm * 16 + q * 4;
#pragma unroll
            for (int r4 = 0; r4 < 4; ++r4) {
                int row = rb + r4;
                if (row < M) {
                    float iv = acc[0][fm][fd][r4] + bi;
                    float ov = acc[1][fm][fd][r4] + bo;
                    float uv = acc[2][fm][fd][r4] + bu;
                    float fl = sigm(acc[3][fm][fd][r4] + bf);
                    float fr = sigm(acc[4][fm][fd][r4] + bf);
                    float clv = 0.f, crv = 0.f;
                    if (!firstLevel) {
                        clv = Cc[(size_t)(2 * row) * 768 + col];
                        crv = Cc[(size_t)(2 * row + 1) * 768 + col];
                    }
                    float c = sigm(iv) * tanhfast(uv) + fl * clv + fr * crv;
                    float h = sigm(ov) * tanhfast(c);
                    if (finalLevel) {
                        outH[row * 768 + col] = h;
                        outC[row * 768 + col] = c;
                    } else {
                        Hn[(size_t)row * 768 + col] = (_Float16)h;
                        Cn[(size_t)row * 768 + col] = c;
                    }
                }
            }
        }
    }
}

extern "C" void kernel_launch(void* const* d_in, const int* in_sizes, int n_in,
                              void* d_out, int out_size, void* d_ws, size_t ws_size,
                              hipStream_t stream)
{
    const float* leaf = (const float*)d_in[0];
    const float* Wiou = (const float*)d_in[1];
    const float* biou = (const float*)d_in[2];
    const float* Uiou = (const float*)d_in[3];
    const float* Wf   = (const float*)d_in[4];
    const float* bfv  = (const float*)d_in[5];
    const float* Uf   = (const float*)d_in[6];

    char* ws = (char*)d_ws;
    _Float16* Bw = (_Float16*)(ws);                  // 5x768x768 fp16 = 5,898,240 B
    _Float16* H0 = (_Float16*)(ws + 5898240);        // 65536x768 fp16
    _Float16* H1 = (_Float16*)(ws + 106561536);      // 32768x768 fp16
    float*    C0 = (float*)(ws + 156893184);         // 32768x768 f32
    float*    C1 = (float*)(ws + 257556480);         // 16384x768 f32

    prep_weights<<<1024, 256, 0, stream>>>(Wiou, Uiou, Wf, Uf, Bw);
    cast_leaves<<<2048, 256, 0, stream>>>(leaf, H0, 50331648 / 8);

    float* out = (float*)d_out;  // [2,8,768]
    _Float16* Hc = H0; _Float16* Hn = H1;
    float* Cc = C1; float* Cn = C0;
    int rows = 65536, level = 0;
    while (rows > 8) {
        int M = rows >> 1;
        int fin = (M == 8) ? 1 : 0;
        int mblocks = (M + 127) / 128;
        tree_level<<<mblocks * 6, 512, 0, stream>>>(Hc, Cc, Bw, biou, bfv,
            Hn, Cn, fin ? out : (float*)nullptr, fin ? out + 6144 : (float*)nullptr,
            M, mblocks, level == 0 ? 1 : 0, fin);
        _Float16* th = Hc; Hc = Hn; Hn = th;
        float* tc = Cc; Cc = Cn; Cn = tc;
        rows = M; ++level;
    }
}

// Round 11
// 1074.138 us; speedup vs baseline: 3.4010x; 1.2422x over previous
//
#include <hip/hip_runtime.h>

// Child-Sum Tree-LSTM, level-synchronous, B=8 L=8192 D=768.
// Per level, 6 fused K=768 GEMM products + LSTM cell epilogue:
//   i,o,u = hs @ (0.5*W_iou + U_iou)^T      (acc0..2)
//   g5 = hs @ (0.5*W_f)^T  (wfx)            (acc3)
//   g6 = hl @ U_f^T                         (acc4)
//   g7 = hs @ U_f^T                         (acc5)
//   fl = sigm(g5+bf+g6); fr = sigm(g5+bf+g7-g6)   [hr@Uf = hs@Uf - hl@Uf]
// Big levels (M>=4096): kernel A, 128x64 tile, 4 waves, 2 blocks/CU,
//   2-deep gload_lds pipeline, counted vmcnt(9), mb-major XCD order.
// Tail levels (M=2048..8): per-level launches of tree_small,
//   128x32 tile, 3 blocks/CU (R7-proven config).  [R10's cooperative
//   fusion failed to launch; reverted to per-level.]

typedef _Float16 half8 __attribute__((ext_vector_type(8)));
typedef float f32x4 __attribute__((ext_vector_type(4)));

#define ROWB 1536        // bytes per 768-elem fp16 row
#define NT 24            // 768 / 32
#define BUFA 36864       // kernel A buffer: A 16384 + B 20480
#define BUFT 26624       // tail buffer: A 16384 + B 10240

__device__ __forceinline__ float sigm(float x){ return 1.f/(1.f+__expf(-x)); }
__device__ __forceinline__ float tanhfast(float x){ return 1.f - 2.f/(1.f+__expf(2.f*x)); }

__device__ __forceinline__ void gload16(const void* g, void* l){
  __builtin_amdgcn_global_load_lds((const __attribute__((address_space(1))) void*)g,
                                   (__attribute__((address_space(3))) void*)l, 16, 0, 0);
}

// Bw: 5 mats of 768x768 fp16: [0..2]=0.5*W_iou+U_iou (i,o,u), [3]=0.5*Wf, [4]=Uf
__global__ void prep_weights(const float* __restrict__ Wiou, const float* __restrict__ Uiou,
                             const float* __restrict__ Wf, const float* __restrict__ Uf,
                             _Float16* __restrict__ Bw)
{
    const int n1 = 2304 * 768, n2 = n1 + 589824, n3 = n2 + 589824;
    int stride = gridDim.x * blockDim.x;
    for (int idx = blockIdx.x * blockDim.x + threadIdx.x; idx < n3; idx += stride) {
        float v;
        if (idx < n1)      v = __fmaf_rn(0.5f, Wiou[idx], Uiou[idx]);
        else if (idx < n2) v = 0.5f * Wf[idx - n1];
        else               v = Uf[idx - n2];
        Bw[idx] = (_Float16)v;
    }
}

__global__ void cast_leaves(const float* __restrict__ x, _Float16* __restrict__ h, int n8)
{
    int stride = gridDim.x * blockDim.x;
    for (int i = blockIdx.x * blockDim.x + threadIdx.x; i < n8; i += stride) {
        float4 v0 = ((const float4*)x)[2 * i];
        float4 v1 = ((const float4*)x)[2 * i + 1];
        half8 o = { (_Float16)v0.x, (_Float16)v0.y, (_Float16)v0.z, (_Float16)v0.w,
                    (_Float16)v1.x, (_Float16)v1.y, (_Float16)v1.z, (_Float16)v1.w };
        ((half8*)h)[i] = o;
    }
}

// ================= kernel A: big levels (M>=4096, M%128==0) =================
// LDS per buffer: A 128 rows x 128B (row r chunk j: jj=j^(r&7), side=jj>>2,
// kchunk=jj&3 of H row 2*(mBase+r)+side); B at +16384: 5 mats x 32 pairs x
// 128B (pair p chunk j: jj=j^(p&7), col=d0+2p+(jj>>2), kchunk=jj&3).
__global__ __launch_bounds__(256, 2) void tree_level(
    const _Float16* __restrict__ Hc, const float* __restrict__ Cc,
    const _Float16* __restrict__ Bw,
    const float* __restrict__ biou, const float* __restrict__ bfv,
    _Float16* __restrict__ Hn, float* __restrict__ Cn,
    int M, int mblocks, int firstLevel)
{
    __shared__ __align__(16) char smem[2 * BUFA];
    const int tid = threadIdx.x;
    const int lane = tid & 63;
    const int w = tid >> 6;        // 0..3
    const int wm = w >> 1;         // 0..1 row-wave (64 rows)
    const int wd = w & 1;          // 0..1 col-wave (32 cols)

    // bijective XCD chunking; mb-major within XCD
    const int nwg = mblocks * 12;
    const int orig = blockIdx.x;
    const int xcd = orig & 7, qx = nwg >> 3, rx = nwg & 7;
    const int v = (xcd < rx ? xcd * (qx + 1) : rx * (qx + 1) + (xcd - rx) * qx) + (orig >> 3);
    const int mb = v / 12;
    const int d0c = v - mb * 12;
    const int mBase = mb * 128;
    const int d0 = d0c * 64;

    // stage sources: 4 A + 5 B per thread
    const int l3 = lane >> 3, j = lane & 7;
    const int jjA = j ^ l3;
    const int rbase = w * 8 + l3;
    unsigned offH[4];
#pragma unroll
    for (int s = 0; s < 4; ++s)
        offH[s] = (unsigned)(2 * (mBase + s * 32 + rbase) + (jjA >> 2)) * ROWB + (jjA & 3) * 16;
    const int pB = w * 8 + l3;
    unsigned offWb[5];
#pragma unroll
    for (int t = 0; t < 5; ++t)
        offWb[t] = (unsigned)(t * 768 + d0 + 2 * pB + (jjA >> 2)) * ROWB + (jjA & 3) * 16;
    const int wK = w * 1024;

#define STAGE_A(bi, ko) do { \
    _Pragma("unroll") for (int s = 0; s < 4; ++s) \
        gload16((const char*)Hc + offH[s] + (ko), smem + (bi) * BUFA + s * 4096 + wK); \
    _Pragma("unroll") for (int t = 0; t < 5; ++t) \
        gload16((const char*)Bw + offWb[t] + (ko), smem + (bi) * BUFA + 16384 + t * 4096 + wK); \
} while (0)

    // compute offsets
    const int q = lane >> 4;
    const int lr16 = lane & 15;
    int offA[4], offB[2];
#pragma unroll
    for (int fm = 0; fm < 4; ++fm) {
        int r = wm * 64 + fm * 16 + lr16;
        offA[fm] = r * 128 + ((q ^ (r & 7)) * 16);
    }
#pragma unroll
    for (int fd = 0; fd < 2; ++fd) {
        int cl = wd * 32 + fd * 16 + lr16;
        int p = cl >> 1;
        int jb = ((cl & 1) * 4 + q) ^ (p & 7);
        offB[fd] = 16384 + p * 128 + jb * 16;
    }

    f32x4 acc[6][4][2];
#pragma unroll
    for (int g = 0; g < 6; ++g)
#pragma unroll
        for (int a = 0; a < 4; ++a)
#pragma unroll
            for (int b2 = 0; b2 < 2; ++b2)
                acc[g][a][b2] = (f32x4){0.f, 0.f, 0.f, 0.f};

    STAGE_A(0, 0);
    int cur = 0;
    for (int kt = 0; kt < NT; ++kt) {
        if (kt + 1 < NT) {
            STAGE_A(cur ^ 1, (kt + 1) * 64);
            asm volatile("s_waitcnt vmcnt(9)" ::: "memory");
        } else {
            asm volatile("s_waitcnt vmcnt(0)" ::: "memory");
        }
        __builtin_amdgcn_s_barrier();
        __builtin_amdgcn_sched_barrier(0);
        const char* bb = smem + cur * BUFA;
        half8 hl[4], hr[4];
#pragma unroll
        for (int fm = 0; fm < 4; ++fm) {
            hl[fm] = *(const half8*)(bb + offA[fm]);
            hr[fm] = *(const half8*)(bb + (offA[fm] ^ 64));
        }
        __builtin_amdgcn_s_setprio(1);
#pragma unroll
        for (int fd = 0; fd < 2; ++fd) {
            const char* bp = bb + offB[fd];
            half8 b0 = *(const half8*)(bp);
            half8 b1 = *(const half8*)(bp + 4096);
            half8 b2 = *(const half8*)(bp + 8192);
            half8 b3 = *(const half8*)(bp + 12288);   // 0.5*Wf
            half8 b4 = *(const half8*)(bp + 16384);   // Uf
#pragma unroll
            for (int fm = 0; fm < 4; ++fm) {
                acc[4][fm][fd] = __builtin_amdgcn_mfma_f32_16x16x32_f16(hl[fm], b4, acc[4][fm][fd], 0, 0, 0);
                half8 hs = hl[fm] + hr[fm];
                acc[0][fm][fd] = __builtin_amdgcn_mfma_f32_16x16x32_f16(hs, b0, acc[0][fm][fd], 0, 0, 0);
                acc[1][fm][fd] = __builtin_amdgcn_mfma_f32_16x16x32_f16(hs, b1, acc[1][fm][fd], 0, 0, 0);
                acc[2][fm][fd] = __builtin_amdgcn_mfma_f32_16x16x32_f16(hs, b2, acc[2][fm][fd], 0, 0, 0);
                acc[3][fm][fd] = __builtin_amdgcn_mfma_f32_16x16x32_f16(hs, b3, acc[3][fm][fd], 0, 0, 0);
                acc[5][fm][fd] = __builtin_amdgcn_mfma_f32_16x16x32_f16(hs, b4, acc[5][fm][fd], 0, 0, 0);
            }
        }
        __builtin_amdgcn_s_setprio(0);
        if (kt + 1 < NT) __builtin_amdgcn_s_barrier();
        cur ^= 1;
    }

#pragma unroll
    for (int fd = 0; fd < 2; ++fd) {
        const int col = d0 + wd * 32 + fd * 16 + lr16;
        const float bi = biou[col];
        const float bo = biou[768 + col];
        const float bu = biou[1536 + col];
        const float bf = bfv[col];
#pragma unroll
        for (int fm = 0; fm < 4; ++fm) {
            const int rb = mBase + wm * 64 + fm * 16 + q * 4;
#pragma unroll
            for (int r4 = 0; r4 < 4; ++r4) {
                int row = rb + r4;
                float iv = acc[0][fm][fd][r4] + bi;
                float ov = acc[1][fm][fd][r4] + bo;
                float uv = acc[2][fm][fd][r4] + bu;
                float wfx = acc[3][fm][fd][r4] + bf;
                float g6 = acc[4][fm][fd][r4];
                float fl = sigm(wfx + g6);
                float fr = sigm(wfx + acc[5][fm][fd][r4] - g6);
                float clv = 0.f, crv = 0.f;
                if (!firstLevel) {
                    clv = Cc[(size_t)(2 * row) * 768 + col];
                    crv = Cc[(size_t)(2 * row + 1) * 768 + col];
                }
                float c = sigm(iv) * tanhfast(uv) + fl * clv + fr * crv;
                float h = sigm(ov) * tanhfast(c);
                Hn[(size_t)row * 768 + col] = (_Float16)h;
                Cn[(size_t)row * 768 + col] = c;
            }
        }
    }
}

// ================= tree_small: tail levels (M=2048..8), per-level =================
__global__ __launch_bounds__(256, 3) void tree_small(
    const _Float16* __restrict__ Hc, const float* __restrict__ Cc,
    const _Float16* __restrict__ Bw,
    const float* __restrict__ biou, const float* __restrict__ bfv,
    _Float16* __restrict__ Hn, float* __restrict__ Cn,
    float* __restrict__ out,
    int M, int finalLevel)
{
    __shared__ __align__(16) char smem[2 * BUFT];
    const int tid = threadIdx.x;
    const int lane = tid & 63;
    const int w = tid >> 6;
    const int wm = w >> 1;
    const int wd = w & 1;
    const int bid = blockIdx.x;
    const int mb = bid / 24;
    const int d0c = bid - mb * 24;
    const int mBase = mb * 128;
    const int d0 = d0c * 32;

    const int l3 = lane >> 3, j = lane & 7;
    const int jj0 = j ^ l3;

    // B stage sources (3 slots, dup trick) + dests
    unsigned offWb[3];
    int dstB[3];
#pragma unroll
    for (int s = 0; s < 3; ++s) {
        int i = s * 4 + w;
        if (i >= 10) i -= 2;
        int t = i >> 1, half = i & 1;
        int p = half * 8 + l3;
        offWb[s] = (unsigned)(t * 768 + d0 + 2 * p + (jj0 >> 2)) * ROWB + (jj0 & 3) * 16;
        dstB[s] = 16384 + t * 2048 + half * 1024;
    }
    // A stage sources (4 slots), clamped to M-1
    unsigned offHa[4];
    int dstA[4];
#pragma unroll
    for (int s = 0; s < 4; ++s) {
        int u = s * 4 + w;
        int gr = mBase + u * 8 + l3;
        if (gr >= M) gr = M - 1;
        offHa[s] = (unsigned)(2 * gr + (jj0 >> 2)) * ROWB + (jj0 & 3) * 16;
        dstA[s] = u * 1024;
    }

#define STAGE_T(bi_, ko) do { \
    _Pragma("unroll") for (int s = 0; s < 4; ++s) \
        gload16((const char*)Hc + offHa[s] + (ko), smem + (bi_) * BUFT + dstA[s]); \
    _Pragma("unroll") for (int s = 0; s < 3; ++s) \
        gload16((const char*)Bw + offWb[s] + (ko), smem + (bi_) * BUFT + dstB[s]); \
} while (0)

    const int q = lane >> 4;
    const int lr16 = lane & 15;
    int offA[4];
#pragma unroll
    for (int fm = 0; fm < 4; ++fm) {
        int r = wm * 64 + fm * 16 + lr16;
        offA[fm] = r * 128 + ((q ^ (r & 7)) * 16);
    }
    int offB;
    {
        int cl = wd * 16 + lr16;
        int p = cl >> 1;
        int jb = ((cl & 1) * 4 + q) ^ (p & 7);
        offB = 16384 + p * 128 + jb * 16;
    }

    f32x4 acc[6][4];
#pragma unroll
    for (int g = 0; g < 6; ++g)
#pragma unroll
        for (int a = 0; a < 4; ++a)
            acc[g][a] = (f32x4){0.f, 0.f, 0.f, 0.f};

    STAGE_T(0, 0);
    int cur = 0;
    for (int kt = 0; kt < NT; ++kt) {
        if (kt + 1 < NT) {
            STAGE_T(cur ^ 1, (kt + 1) * 64);
            asm volatile("s_waitcnt vmcnt(7)" ::: "memory");
        } else {
            asm volatile("s_waitcnt vmcnt(0)" ::: "memory");
        }
        __builtin_amdgcn_s_barrier();
        __builtin_amdgcn_sched_barrier(0);
        const char* bb = smem + cur * BUFT;
        half8 b0 = *(const half8*)(bb + offB);
        half8 b1 = *(const half8*)(bb + offB + 2048);
        half8 b2 = *(const half8*)(bb + offB + 4096);
        half8 b3 = *(const half8*)(bb + offB + 6144);   // 0.5*Wf
        half8 b4 = *(const half8*)(bb + offB + 8192);   // Uf
        __builtin_amdgcn_s_setprio(1);
#pragma unroll
        for (int fm = 0; fm < 4; ++fm) {
            half8 hl = *(const half8*)(bb + offA[fm]);
            half8 hr = *(const half8*)(bb + (offA[fm] ^ 64));
            acc[4][fm] = __builtin_amdgcn_mfma_f32_16x16x32_f16(hl, b4, acc[4][fm], 0, 0, 0);
            half8 hs = hl + hr;
            acc[0][fm] = __builtin_amdgcn_mfma_f32_16x16x32_f16(hs, b0, acc[0][fm], 0, 0, 0);
            acc[1][fm] = __builtin_amdgcn_mfma_f32_16x16x32_f16(hs, b1, acc[1][fm], 0, 0, 0);
            acc[2][fm] = __builtin_amdgcn_mfma_f32_16x16x32_f16(hs, b2, acc[2][fm], 0, 0, 0);
            acc[3][fm] = __builtin_amdgcn_mfma_f32_16x16x32_f16(hs, b3, acc[3][fm], 0, 0, 0);
            acc[5][fm] = __builtin_amdgcn_mfma_f32_16x16x32_f16(hs, b4, acc[5][fm], 0, 0, 0);
        }
        __builtin_amdgcn_s_setprio(0);
        if (kt + 1 < NT) __builtin_amdgcn_s_barrier();
        cur ^= 1;
    }

    const int col = d0 + wd * 16 + lr16;
    const float bi = biou[col];
    const float bo = biou[768 + col];
    const float bu = biou[1536 + col];
    const float bf = bfv[col];
#pragma unroll
    for (int fm = 0; fm < 4; ++fm) {
        const int rb = mBase + wm * 64 + fm * 16 + q * 4;
#pragma unroll
        for (int r4 = 0; r4 < 4; ++r4) {
            int row = rb + r4;
            if (row < M) {
                float iv = acc[0][fm][r4] + bi;
                float ov = acc[1][fm][r4] + bo;
                float uv = acc[2][fm][r4] + bu;
                float wfx = acc[3][fm][r4] + bf;
                float g6 = acc[4][fm][r4];
                float fl = sigm(wfx + g6);
                float fr = sigm(wfx + acc[5][fm][r4] - g6);
                float clv = Cc[(size_t)(2 * row) * 768 + col];
                float crv = Cc[(size_t)(2 * row + 1) * 768 + col];
                float c = sigm(iv) * tanhfast(uv) + fl * clv + fr * crv;
                float h = sigm(ov) * tanhfast(c);
                if (finalLevel) {
                    out[row * 768 + col] = h;
                    out[6144 + row * 768 + col] = c;
                } else {
                    Hn[(size_t)row * 768 + col] = (_Float16)h;
                    Cn[(size_t)row * 768 + col] = c;
                }
            }
        }
    }
}

extern "C" void kernel_launch(void* const* d_in, const int* in_sizes, int n_in,
                              void* d_out, int out_size, void* d_ws, size_t ws_size,
                              hipStream_t stream)
{
    const float* leaf = (const float*)d_in[0];
    const float* Wiou = (const float*)d_in[1];
    const float* biou = (const float*)d_in[2];
    const float* Uiou = (const float*)d_in[3];
    const float* Wf   = (const float*)d_in[4];
    const float* bfv  = (const float*)d_in[5];
    const float* Uf   = (const float*)d_in[6];

    char* ws = (char*)d_ws;
    _Float16* Bw = (_Float16*)(ws);                  // 5x768x768 fp16 = 5,898,240 B
    _Float16* H0 = (_Float16*)(ws + 5898240);        // 65536x768 fp16
    _Float16* H1 = (_Float16*)(ws + 106561536);      // 32768x768 fp16
    float*    C0 = (float*)(ws + 156893184);         // 32768x768 f32
    float*    C1 = (float*)(ws + 257556480);         // 16384x768 f32

    prep_weights<<<1024, 256, 0, stream>>>(Wiou, Uiou, Wf, Uf, Bw);
    cast_leaves<<<2048, 256, 0, stream>>>(leaf, H0, 50331648 / 8);

    float* out = (float*)d_out;  // [2,8,768]
    _Float16* Hc = H0; _Float16* Hn = H1;
    float* Cc = C1; float* Cn = C0;
    int rows = 65536, level = 0;
    while (rows > 8) {
        int M = rows >> 1;
        if (M >= 4096) {
            int mblocks = M / 128;
            tree_level<<<mblocks * 12, 256, 0, stream>>>(Hc, Cc, Bw, biou, bfv,
                Hn, Cn, M, mblocks, level == 0 ? 1 : 0);
        } else {
            int mblocks = (M + 127) / 128;
            int fin = (M == 8) ? 1 : 0;
            tree_small<<<mblocks * 24, 256, 0, stream>>>(Hc, Cc, Bw, biou, bfv,
                Hn, Cn, out, M, fin);
        }
        _Float16* th = Hc; Hc = Hn; Hn = th;
        float* tc = Cc; Cc = Cn; Cn = tc;
        rows = M; ++level;
    }
}